// Round 6
// baseline (195.606 us; speedup 1.0000x reference)
//
#include <hip/hip_runtime.h>

#define DH 128

typedef __bf16 bf16x8 __attribute__((ext_vector_type(8)));
typedef float f32x4 __attribute__((ext_vector_type(4)));

__device__ __forceinline__ ushort f2b(float f) {
  union { float f; unsigned u; } c; c.f = f;
  unsigned u = c.u;
  unsigned r = (u + 0x7fffu + ((u >> 16) & 1u)) >> 16;
  return (ushort)r;
}
__device__ __forceinline__ float b2f_lo(unsigned v) {
  union { unsigned u; float f; } c; c.u = v << 16;
  return c.f;
}
__device__ __forceinline__ float b2f_hi(unsigned v) {
  union { unsigned u; float f; } c; c.u = v & 0xffff0000u;
  return c.f;
}

// ---- zero deg (runtime hipMemsetAsync fill kernel costs 43us for 200KB!) ----
__global__ void k_zero(int4* __restrict__ p, int n4) {
  int i = blockIdx.x * 256 + threadIdx.x;
  if (i < n4) p[i] = int4{0, 0, 0, 0};
}

// ---- fused: convert f32->bf16 | weight pack (NO hist: streaming evicts deg from L2) ----
__global__ void k_prep0(const float* __restrict__ x, ushort* __restrict__ xb, long n8,
                        int nConv,
                        const float* __restrict__ Ws1, const float* __restrict__ Wn1,
                        const float* __restrict__ Ws2, const float* __restrict__ Wn2,
                        ushort* __restrict__ Wp1, ushort* __restrict__ Wp2) {
  int bid = blockIdx.x;
  if (bid < nConv) {
    long i = (long)bid * 256 + threadIdx.x;
    if (i >= n8) return;
    const float4* p = (const float4*)x + i * 2;
    float4 a = p[0], b = p[1];
    uint4 o;
    o.x = (unsigned)f2b(a.x) | ((unsigned)f2b(a.y) << 16);
    o.y = (unsigned)f2b(a.z) | ((unsigned)f2b(a.w) << 16);
    o.z = (unsigned)f2b(b.x) | ((unsigned)f2b(b.y) << 16);
    o.w = (unsigned)f2b(b.z) | ((unsigned)f2b(b.w) << 16);
    ((uint4*)xb)[i] = o;
  } else {
    int idx = (bid - nConv) * 256 + threadIdx.x;
    if (idx >= 2 * 8 * 8 * 64 * 8) return;
    int layer = idx >> 15;
    int t = idx & 32767;
    int j = t & 7;
    int lane = (t >> 3) & 63;
    int cb = (t >> 9) & 7;
    int s = (t >> 12) & 7;
    int col = cb * 16 + (lane & 15);
    int k = s * 32 + ((lane >> 4) * 8) + j;
    const float* Wself = layer ? Ws2 : Ws1;
    const float* Wneigh = layer ? Wn2 : Wn1;
    float v = (k < 128) ? Wself[k * 128 + col] : Wneigh[(k - 128) * 128 + col];
    (layer ? Wp2 : Wp1)[t] = f2b(v);
  }
}

// ---- degree histogram, XCD-partitioned by dst range ----
__global__ void k_hist8(const int* __restrict__ dst, int* __restrict__ deg,
                        int E, int nper, int chunkSz) {
  int part = blockIdx.x & 7;
  int chunk = blockIdx.x >> 3;
  int lo = part * nper, hi = lo + nper;
  int base = chunk * chunkSz;
  int end = min(base + chunkSz, E);
  for (int i = base + threadIdx.x; i < end; i += 256) {
    int d = dst[i];
    if (d >= lo && d < hi) atomicAdd(&deg[d], 1);
  }
}

// ---- block-level inclusive scan (1024/block) ----
__global__ void k_scan1(const int* __restrict__ deg, int* __restrict__ rowptr,
                        int* __restrict__ bsum, int N) {
  __shared__ int s[1024];
  int t = threadIdx.x, i = blockIdx.x * 1024 + t;
  int v = (i < N) ? deg[i] : 0;
  s[t] = v;
  __syncthreads();
  for (int off = 1; off < 1024; off <<= 1) {
    int u = (t >= off) ? s[t - off] : 0;
    __syncthreads();
    s[t] += u;
    __syncthreads();
  }
  if (i < N) rowptr[i + 1] = s[t];
  if (t == 1023) bsum[blockIdx.x] = s[1023];
}

// ---- exclusive scan of block sums: one wave shfl scan (nb <= 64 fast path) ----
__global__ void k_scan2(int* bsum, int nb) {
  if (nb <= 64) {
    int l = threadIdx.x;
    int v = (l < nb) ? bsum[l] : 0;
    for (int off = 1; off < 64; off <<= 1) {
      int u = __shfl_up(v, off);
      if (l >= off) v += u;
    }
    int ex = __shfl_up(v, 1);
    if (l == 0) ex = 0;
    if (l < nb) bsum[l] = ex;
  } else if (threadIdx.x == 0) {
    int run = 0;
    for (int i = 0; i < nb; ++i) { int v = bsum[i]; bsum[i] = run; run += v; }
  }
}

// ---- add block offsets + emit cursor (=rowptr[i]) and invdeg ----
__global__ void k_scan3(int* __restrict__ rowptr, const int* __restrict__ bsum,
                        const int* __restrict__ deg, int* __restrict__ cursor,
                        float* __restrict__ invdeg, int N) {
  int i = blockIdx.x * 1024 + threadIdx.x;
  if (i == 0) rowptr[0] = 0;
  if (i < N) {
    int d = deg[i];
    int inc = rowptr[i + 1] + bsum[blockIdx.x];
    rowptr[i + 1] = inc;
    cursor[i] = inc - d;
    invdeg[i] = 1.0f / fmaxf((float)d, 1.0f);
  }
}

// ---- CSR fill, XCD-partitioned by dst range ----
__global__ void k_fill8(const int* __restrict__ src, const int* __restrict__ dst,
                        int* __restrict__ cursor, int* __restrict__ colsrc,
                        int E, int nper, int chunkSz) {
  int part = blockIdx.x & 7;
  int chunk = blockIdx.x >> 3;
  int lo = part * nper, hi = lo + nper;
  int base = chunk * chunkSz;
  int end = min(base + chunkSz, E);
  for (int i = base + threadIdx.x; i < end; i += 256) {
    int d = dst[i];
    int s = src[i];
    if (d >= lo && d < hi) {
      int pos = atomicAdd(&cursor[d], 1);
      colsrc[pos] = s;
    }
  }
}

__device__ __forceinline__ void acc8(float* a, uint4 v) {
  a[0] += b2f_lo(v.x); a[1] += b2f_hi(v.x);
  a[2] += b2f_lo(v.y); a[3] += b2f_hi(v.y);
  a[4] += b2f_lo(v.z); a[5] += b2f_hi(v.z);
  a[6] += b2f_lo(v.w); a[7] += b2f_hi(v.w);
}

// ---- gather aggregation: mean of in-neighbor rows, bf16 in/out, f32 accum ----
// 256 threads = 16 groups of 16 lanes; group = one node; lane = 8 feats (16B).
// Edge loop unrolled x8: 8 independent gathers in flight per lane (latency-bound fix).
__global__ void k_aggregate(const uint4* __restrict__ feat4, const int* __restrict__ rowptr,
                            const int* __restrict__ colsrc, const float* __restrict__ invdeg,
                            uint4* __restrict__ out4, int N) {
  int g = threadIdx.x >> 4, l = threadIdx.x & 15;
  int node = blockIdx.x * 16 + g;
  if (node >= N) return;
  int beg = rowptr[node], end = rowptr[node + 1];
  float a[8] = {0.f, 0.f, 0.f, 0.f, 0.f, 0.f, 0.f, 0.f};
  int e = beg;
  for (; e + 8 <= end; e += 8) {
    int s0 = colsrc[e], s1 = colsrc[e + 1], s2 = colsrc[e + 2], s3 = colsrc[e + 3];
    int s4 = colsrc[e + 4], s5 = colsrc[e + 5], s6 = colsrc[e + 6], s7 = colsrc[e + 7];
    uint4 v0 = feat4[(size_t)s0 * 16 + l];
    uint4 v1 = feat4[(size_t)s1 * 16 + l];
    uint4 v2 = feat4[(size_t)s2 * 16 + l];
    uint4 v3 = feat4[(size_t)s3 * 16 + l];
    uint4 v4 = feat4[(size_t)s4 * 16 + l];
    uint4 v5 = feat4[(size_t)s5 * 16 + l];
    uint4 v6 = feat4[(size_t)s6 * 16 + l];
    uint4 v7 = feat4[(size_t)s7 * 16 + l];
    acc8(a, v0); acc8(a, v1); acc8(a, v2); acc8(a, v3);
    acc8(a, v4); acc8(a, v5); acc8(a, v6); acc8(a, v7);
  }
  for (; e + 4 <= end; e += 4) {
    int s0 = colsrc[e], s1 = colsrc[e + 1], s2 = colsrc[e + 2], s3 = colsrc[e + 3];
    uint4 v0 = feat4[(size_t)s0 * 16 + l];
    uint4 v1 = feat4[(size_t)s1 * 16 + l];
    uint4 v2 = feat4[(size_t)s2 * 16 + l];
    uint4 v3 = feat4[(size_t)s3 * 16 + l];
    acc8(a, v0); acc8(a, v1); acc8(a, v2); acc8(a, v3);
  }
  for (; e < end; ++e) {
    uint4 v = feat4[(size_t)colsrc[e] * 16 + l];
    acc8(a, v);
  }
  float sc = invdeg[node];
  uint4 o;
  o.x = (unsigned)f2b(a[0] * sc) | ((unsigned)f2b(a[1] * sc) << 16);
  o.y = (unsigned)f2b(a[2] * sc) | ((unsigned)f2b(a[3] * sc) << 16);
  o.z = (unsigned)f2b(a[4] * sc) | ((unsigned)f2b(a[5] * sc) << 16);
  o.w = (unsigned)f2b(a[6] * sc) | ((unsigned)f2b(a[7] * sc) << 16);
  out4[(size_t)node * 16 + l] = o;
}

// ---- GEMM: out[i][:] = self[i]@Wself + neigh[i]@Wneigh + b, optional relu ----
// K=256 combined (ksteps 0-3 self, 4-7 neigh). 4 waves x 16 rows x 128 cols.
template <int RELU, int OUTF32>
__global__ void k_gemm(const ushort* __restrict__ selfb, const ushort* __restrict__ neighb,
                       const ushort* __restrict__ Wp, const float* __restrict__ bias,
                       void* __restrict__ outp, int M) {
  int wave = threadIdx.x >> 6, lane = threadIdx.x & 63;
  int rowA = blockIdx.x * 64 + wave * 16 + (lane & 15);
  int kq = lane >> 4;
  bool valid = rowA < M;
  size_t abase = (size_t)rowA * DH + kq * 8;
  f32x4 acc[8] = {};
#pragma unroll
  for (int hf = 0; hf < 2; ++hf) {
    const ushort* S = hf ? neighb : selfb;
#pragma unroll
    for (int ks = 0; ks < 4; ++ks) {
      bf16x8 a = {};
      if (valid) a = __builtin_bit_cast(bf16x8, *(const uint4*)(S + abase + ks * 32));
      int sg = hf * 4 + ks;
      const ushort* wp = Wp + sg * 4096 + lane * 8;
#pragma unroll
      for (int cb = 0; cb < 8; ++cb) {
        bf16x8 b = __builtin_bit_cast(bf16x8, *(const uint4*)(wp + cb * 512));
        acc[cb] = __builtin_amdgcn_mfma_f32_16x16x32_bf16(a, b, acc[cb], 0, 0, 0);
      }
    }
  }
  // C/D layout: col = lane&15, row = (lane>>4)*4 + reg
  int col = lane & 15;
  int row0 = blockIdx.x * 64 + wave * 16 + (lane >> 4) * 4;
#pragma unroll
  for (int cb = 0; cb < 8; ++cb) {
    float bv = bias[cb * 16 + col];
#pragma unroll
    for (int j = 0; j < 4; ++j) {
      int rr = row0 + j;
      if (rr < M) {
        float v = acc[cb][j] + bv;
        if (RELU) v = fmaxf(v, 0.f);
        if (OUTF32)
          ((float*)outp)[(size_t)rr * DH + cb * 16 + col] = v;
        else
          ((ushort*)outp)[(size_t)rr * DH + cb * 16 + col] = f2b(v);
      }
    }
  }
}

extern "C" void kernel_launch(void* const* d_in, const int* in_sizes, int n_in,
                              void* d_out, int out_size, void* d_ws, size_t ws_size,
                              hipStream_t stream) {
  const float* x = (const float*)d_in[0];
  const int* src = (const int*)d_in[1];
  const int* dst = (const int*)d_in[2];
  const float* Wself1 = (const float*)d_in[3];
  const float* Wneigh1 = (const float*)d_in[4];
  const float* b1 = (const float*)d_in[5];
  const float* Wself2 = (const float*)d_in[6];
  const float* Wneigh2 = (const float*)d_in[7];
  const float* b2 = (const float*)d_in[8];
  int N = in_sizes[0] / DH;
  int E = in_sizes[1];

  char* w = (char*)d_ws;
  auto alloc = [&](size_t bytes) {
    char* p = w;
    w += (bytes + 255) & ~(size_t)255;
    return p;
  };
  ushort* xb = (ushort*)alloc((size_t)N * DH * 2);
  ushort* hb = (ushort*)alloc((size_t)N * DH * 2);
  ushort* nb = (ushort*)alloc((size_t)N * DH * 2);
  ushort* Wp1 = (ushort*)alloc(32768 * 2);
  ushort* Wp2 = (ushort*)alloc(32768 * 2);
  int* deg = (int*)alloc((size_t)N * 4);
  int* rowptr = (int*)alloc((size_t)(N + 1) * 4);
  int* cursor = (int*)alloc((size_t)N * 4);
  float* invdeg = (float*)alloc((size_t)N * 4);
  int* colsrc = (int*)alloc((size_t)E * 4);
  int* bsum = (int*)alloc(4096);

  int n4 = (N + 3) / 4;
  k_zero<<<(n4 + 255) / 256, 256, 0, stream>>>((int4*)deg, n4);

  long n8 = (long)N * DH / 8;
  int nConv = (int)((n8 + 255) / 256);
  int nPack = (2 * 8 * 8 * 64 * 8 + 255) / 256;
  k_prep0<<<nConv + nPack, 256, 0, stream>>>(x, xb, n8, nConv,
                                             Wself1, Wneigh1, Wself2, Wneigh2, Wp1, Wp2);

  int nper = (N + 7) / 8;
  int nchunk = 256;
  int chunkSz = (E + nchunk - 1) / nchunk;
  k_hist8<<<nchunk * 8, 256, 0, stream>>>(dst, deg, E, nper, chunkSz);

  int nb1k = (N + 1023) / 1024;
  k_scan1<<<nb1k, 1024, 0, stream>>>(deg, rowptr, bsum, N);
  k_scan2<<<1, 64, 0, stream>>>(bsum, nb1k);
  k_scan3<<<nb1k, 1024, 0, stream>>>(rowptr, bsum, deg, cursor, invdeg, N);
  k_fill8<<<nchunk * 8, 256, 0, stream>>>(src, dst, cursor, colsrc, E, nper, chunkSz);

  int aggb = (N + 15) / 16;
  int gb = (N + 63) / 64;
  // layer 1
  k_aggregate<<<aggb, 256, 0, stream>>>((const uint4*)xb, rowptr, colsrc, invdeg, (uint4*)nb, N);
  k_gemm<1, 0><<<gb, 256, 0, stream>>>(xb, nb, Wp1, b1, hb, N);
  // layer 2
  k_aggregate<<<aggb, 256, 0, stream>>>((const uint4*)hb, rowptr, colsrc, invdeg, (uint4*)nb, N);
  k_gemm<0, 1><<<gb, 256, 0, stream>>>(hb, nb, Wp2, b2, d_out, N);
}

// Round 7
// 195.000 us; speedup vs baseline: 1.0031x; 1.0031x over previous
//
#include <hip/hip_runtime.h>

#define DH 128
#define RSH 13  // src-range shift: 8 buckets of 8192 nodes (2MB feature slices)
#define NB 8    // buckets per node

typedef __bf16 bf16x8 __attribute__((ext_vector_type(8)));
typedef float f32x4 __attribute__((ext_vector_type(4)));

__device__ __forceinline__ ushort f2b(float f) {
  union { float f; unsigned u; } c; c.f = f;
  unsigned u = c.u;
  unsigned r = (u + 0x7fffu + ((u >> 16) & 1u)) >> 16;
  return (ushort)r;
}
__device__ __forceinline__ float b2f_lo(unsigned v) {
  union { unsigned u; float f; } c; c.u = v << 16;
  return c.f;
}
__device__ __forceinline__ float b2f_hi(unsigned v) {
  union { unsigned u; float f; } c; c.u = v & 0xffff0000u;
  return c.f;
}

// ---- zero (runtime hipMemsetAsync fill kernel costs 43us for small buffers) ----
__global__ void k_zero(int4* __restrict__ p, int n4) {
  int i = blockIdx.x * 256 + threadIdx.x;
  if (i < n4) p[i] = int4{0, 0, 0, 0};
}

// ---- fused: convert f32->bf16 | weight pack (NO hist: streaming evicts deg from L2) ----
__global__ void k_prep0(const float* __restrict__ x, ushort* __restrict__ xb, long n8,
                        int nConv,
                        const float* __restrict__ Ws1, const float* __restrict__ Wn1,
                        const float* __restrict__ Ws2, const float* __restrict__ Wn2,
                        ushort* __restrict__ Wp1, ushort* __restrict__ Wp2) {
  int bid = blockIdx.x;
  if (bid < nConv) {
    long i = (long)bid * 256 + threadIdx.x;
    if (i >= n8) return;
    const float4* p = (const float4*)x + i * 2;
    float4 a = p[0], b = p[1];
    uint4 o;
    o.x = (unsigned)f2b(a.x) | ((unsigned)f2b(a.y) << 16);
    o.y = (unsigned)f2b(a.z) | ((unsigned)f2b(a.w) << 16);
    o.z = (unsigned)f2b(b.x) | ((unsigned)f2b(b.y) << 16);
    o.w = (unsigned)f2b(b.z) | ((unsigned)f2b(b.w) << 16);
    ((uint4*)xb)[i] = o;
  } else {
    int idx = (bid - nConv) * 256 + threadIdx.x;
    if (idx >= 2 * 8 * 8 * 64 * 8) return;
    int layer = idx >> 15;
    int t = idx & 32767;
    int j = t & 7;
    int lane = (t >> 3) & 63;
    int cb = (t >> 9) & 7;
    int s = (t >> 12) & 7;
    int col = cb * 16 + (lane & 15);
    int k = s * 32 + ((lane >> 4) * 8) + j;
    const float* Wself = layer ? Ws2 : Ws1;
    const float* Wneigh = layer ? Wn2 : Wn1;
    float v = (k < 128) ? Wself[k * 128 + col] : Wneigh[(k - 128) * 128 + col];
    (layer ? Wp2 : Wp1)[t] = f2b(v);
  }
}

// ---- bucketed degree histogram, XCD-partitioned by dst range ----
// deg8[dst*8 + (src>>RSH)]: per-(node, src-range) counts.
__global__ void k_hist8(const int* __restrict__ src, const int* __restrict__ dst,
                        int* __restrict__ deg8, int E, int nper, int chunkSz) {
  int part = blockIdx.x & 7;
  int chunk = blockIdx.x >> 3;
  int lo = part * nper, hi = lo + nper;
  int base = chunk * chunkSz;
  int end = min(base + chunkSz, E);
  for (int i = base + threadIdx.x; i < end; i += 256) {
    int d = dst[i];
    int s = src[i];
    if (d >= lo && d < hi) atomicAdd(&deg8[(size_t)d * NB + (s >> RSH)], 1);
  }
}

// ---- block-level inclusive scan (1024/block) over deg8 (8N entries) ----
__global__ void k_scan1(const int* __restrict__ deg8, int* __restrict__ rowptr8,
                        int* __restrict__ bsum, int M) {
  __shared__ int s[1024];
  int t = threadIdx.x, i = blockIdx.x * 1024 + t;
  int v = (i < M) ? deg8[i] : 0;
  s[t] = v;
  __syncthreads();
  for (int off = 1; off < 1024; off <<= 1) {
    int u = (t >= off) ? s[t - off] : 0;
    __syncthreads();
    s[t] += u;
    __syncthreads();
  }
  if (i < M) rowptr8[i + 1] = s[t];
  if (t == 1023) bsum[blockIdx.x] = s[1023];
}

// ---- exclusive scan of block sums: one block, LDS scan (nb <= 1024) ----
__global__ void k_scan2(int* bsum, int nb) {
  if (nb <= 1024) {
    __shared__ int s[1024];
    int t = threadIdx.x;
    int v = (t < nb) ? bsum[t] : 0;
    s[t] = v;
    __syncthreads();
    for (int off = 1; off < 1024; off <<= 1) {
      int u = (t >= off) ? s[t - off] : 0;
      __syncthreads();
      s[t] += u;
      __syncthreads();
    }
    if (t < nb) bsum[t] = (t == 0) ? 0 : s[t - 1];
  } else if (threadIdx.x == 0 && blockIdx.x == 0) {
    int run = 0;
    for (int i = 0; i < nb; ++i) { int v = bsum[i]; bsum[i] = run; run += v; }
  }
}

// ---- add block offsets + emit cursor8 (=exclusive start of each (node,range) slot) ----
__global__ void k_scan3(int* __restrict__ rowptr8, const int* __restrict__ bsum,
                        const int* __restrict__ deg8, int* __restrict__ cursor8, int M) {
  int i = blockIdx.x * 1024 + threadIdx.x;
  if (i == 0) rowptr8[0] = 0;
  if (i < M) {
    int d = deg8[i];
    int inc = rowptr8[i + 1] + bsum[blockIdx.x];
    rowptr8[i + 1] = inc;
    cursor8[i] = inc - d;
  }
}

// ---- invdeg from bucketed rowptr ----
__global__ void k_invd(const int* __restrict__ rowptr8, float* __restrict__ invdeg, int N) {
  int i = blockIdx.x * 256 + threadIdx.x;
  if (i < N) {
    int d = rowptr8[i * NB + NB] - rowptr8[i * NB];
    invdeg[i] = 1.0f / fmaxf((float)d, 1.0f);
  }
}

// ---- CSR fill, bucketed by src range, XCD-partitioned by dst range ----
// colsrc within each node's segment is grouped by src>>RSH: the aggregate's
// gathers then sweep the feature table range-by-range (L2-resident slices).
__global__ void k_fill8(const int* __restrict__ src, const int* __restrict__ dst,
                        int* __restrict__ cursor8, int* __restrict__ colsrc,
                        int E, int nper, int chunkSz) {
  int part = blockIdx.x & 7;
  int chunk = blockIdx.x >> 3;
  int lo = part * nper, hi = lo + nper;
  int base = chunk * chunkSz;
  int end = min(base + chunkSz, E);
  for (int i = base + threadIdx.x; i < end; i += 256) {
    int d = dst[i];
    int s = src[i];
    if (d >= lo && d < hi) {
      int pos = atomicAdd(&cursor8[(size_t)d * NB + (s >> RSH)], 1);
      colsrc[pos] = s;
    }
  }
}

__device__ __forceinline__ void acc8(float* a, uint4 v) {
  a[0] += b2f_lo(v.x); a[1] += b2f_hi(v.x);
  a[2] += b2f_lo(v.y); a[3] += b2f_hi(v.y);
  a[4] += b2f_lo(v.z); a[5] += b2f_hi(v.z);
  a[6] += b2f_lo(v.w); a[7] += b2f_hi(v.w);
}

// ---- gather aggregation: mean of in-neighbor rows, bf16 in/out, f32 accum ----
// 256 threads = 16 groups of 16 lanes; group = one node; lane = 8 feats (16B).
// Edge loop unrolled x8. colsrc is range-sorted per node (see k_fill8) so the
// concurrent gather window stays L2-resident.
__global__ void k_aggregate(const uint4* __restrict__ feat4, const int* __restrict__ rowptr8,
                            const int* __restrict__ colsrc, const float* __restrict__ invdeg,
                            uint4* __restrict__ out4, int N) {
  int g = threadIdx.x >> 4, l = threadIdx.x & 15;
  int node = blockIdx.x * 16 + g;
  if (node >= N) return;
  int beg = rowptr8[node * NB], end = rowptr8[node * NB + NB];
  float a[8] = {0.f, 0.f, 0.f, 0.f, 0.f, 0.f, 0.f, 0.f};
  int e = beg;
  for (; e + 8 <= end; e += 8) {
    int s0 = colsrc[e], s1 = colsrc[e + 1], s2 = colsrc[e + 2], s3 = colsrc[e + 3];
    int s4 = colsrc[e + 4], s5 = colsrc[e + 5], s6 = colsrc[e + 6], s7 = colsrc[e + 7];
    uint4 v0 = feat4[(size_t)s0 * 16 + l];
    uint4 v1 = feat4[(size_t)s1 * 16 + l];
    uint4 v2 = feat4[(size_t)s2 * 16 + l];
    uint4 v3 = feat4[(size_t)s3 * 16 + l];
    uint4 v4 = feat4[(size_t)s4 * 16 + l];
    uint4 v5 = feat4[(size_t)s5 * 16 + l];
    uint4 v6 = feat4[(size_t)s6 * 16 + l];
    uint4 v7 = feat4[(size_t)s7 * 16 + l];
    acc8(a, v0); acc8(a, v1); acc8(a, v2); acc8(a, v3);
    acc8(a, v4); acc8(a, v5); acc8(a, v6); acc8(a, v7);
  }
  for (; e + 4 <= end; e += 4) {
    int s0 = colsrc[e], s1 = colsrc[e + 1], s2 = colsrc[e + 2], s3 = colsrc[e + 3];
    uint4 v0 = feat4[(size_t)s0 * 16 + l];
    uint4 v1 = feat4[(size_t)s1 * 16 + l];
    uint4 v2 = feat4[(size_t)s2 * 16 + l];
    uint4 v3 = feat4[(size_t)s3 * 16 + l];
    acc8(a, v0); acc8(a, v1); acc8(a, v2); acc8(a, v3);
  }
  for (; e < end; ++e) {
    uint4 v = feat4[(size_t)colsrc[e] * 16 + l];
    acc8(a, v);
  }
  float sc = invdeg[node];
  uint4 o;
  o.x = (unsigned)f2b(a[0] * sc) | ((unsigned)f2b(a[1] * sc) << 16);
  o.y = (unsigned)f2b(a[2] * sc) | ((unsigned)f2b(a[3] * sc) << 16);
  o.z = (unsigned)f2b(a[4] * sc) | ((unsigned)f2b(a[5] * sc) << 16);
  o.w = (unsigned)f2b(a[6] * sc) | ((unsigned)f2b(a[7] * sc) << 16);
  out4[(size_t)node * 16 + l] = o;
}

// ---- GEMM: out[i][:] = self[i]@Wself + neigh[i]@Wneigh + b, optional relu ----
// K=256 combined (ksteps 0-3 self, 4-7 neigh). 4 waves x 16 rows x 128 cols.
template <int RELU, int OUTF32>
__global__ void k_gemm(const ushort* __restrict__ selfb, const ushort* __restrict__ neighb,
                       const ushort* __restrict__ Wp, const float* __restrict__ bias,
                       void* __restrict__ outp, int M) {
  int wave = threadIdx.x >> 6, lane = threadIdx.x & 63;
  int rowA = blockIdx.x * 64 + wave * 16 + (lane & 15);
  int kq = lane >> 4;
  bool valid = rowA < M;
  size_t abase = (size_t)rowA * DH + kq * 8;
  f32x4 acc[8] = {};
#pragma unroll
  for (int hf = 0; hf < 2; ++hf) {
    const ushort* S = hf ? neighb : selfb;
#pragma unroll
    for (int ks = 0; ks < 4; ++ks) {
      bf16x8 a = {};
      if (valid) a = __builtin_bit_cast(bf16x8, *(const uint4*)(S + abase + ks * 32));
      int sg = hf * 4 + ks;
      const ushort* wp = Wp + sg * 4096 + lane * 8;
#pragma unroll
      for (int cb = 0; cb < 8; ++cb) {
        bf16x8 b = __builtin_bit_cast(bf16x8, *(const uint4*)(wp + cb * 512));
        acc[cb] = __builtin_amdgcn_mfma_f32_16x16x32_bf16(a, b, acc[cb], 0, 0, 0);
      }
    }
  }
  // C/D layout: col = lane&15, row = (lane>>4)*4 + reg
  int col = lane & 15;
  int row0 = blockIdx.x * 64 + wave * 16 + (lane >> 4) * 4;
#pragma unroll
  for (int cb = 0; cb < 8; ++cb) {
    float bv = bias[cb * 16 + col];
#pragma unroll
    for (int j = 0; j < 4; ++j) {
      int rr = row0 + j;
      if (rr < M) {
        float v = acc[cb][j] + bv;
        if (RELU) v = fmaxf(v, 0.f);
        if (OUTF32)
          ((float*)outp)[(size_t)rr * DH + cb * 16 + col] = v;
        else
          ((ushort*)outp)[(size_t)rr * DH + cb * 16 + col] = f2b(v);
      }
    }
  }
}

extern "C" void kernel_launch(void* const* d_in, const int* in_sizes, int n_in,
                              void* d_out, int out_size, void* d_ws, size_t ws_size,
                              hipStream_t stream) {
  const float* x = (const float*)d_in[0];
  const int* src = (const int*)d_in[1];
  const int* dst = (const int*)d_in[2];
  const float* Wself1 = (const float*)d_in[3];
  const float* Wneigh1 = (const float*)d_in[4];
  const float* b1 = (const float*)d_in[5];
  const float* Wself2 = (const float*)d_in[6];
  const float* Wneigh2 = (const float*)d_in[7];
  const float* b2 = (const float*)d_in[8];
  int N = in_sizes[0] / DH;
  int E = in_sizes[1];

  char* w = (char*)d_ws;
  auto alloc = [&](size_t bytes) {
    char* p = w;
    w += (bytes + 255) & ~(size_t)255;
    return p;
  };
  ushort* xb = (ushort*)alloc((size_t)N * DH * 2);
  ushort* hb = (ushort*)alloc((size_t)N * DH * 2);
  ushort* nb = (ushort*)alloc((size_t)N * DH * 2);
  ushort* Wp1 = (ushort*)alloc(32768 * 2);
  ushort* Wp2 = (ushort*)alloc(32768 * 2);
  int* deg8 = (int*)alloc((size_t)N * NB * 4);
  int* rowptr8 = (int*)alloc(((size_t)N * NB + 1) * 4);
  int* cursor8 = (int*)alloc((size_t)N * NB * 4);
  float* invdeg = (float*)alloc((size_t)N * 4);
  int* colsrc = (int*)alloc((size_t)E * 4);
  int* bsum = (int*)alloc(4096);

  int M8 = N * NB;
  int n4 = (M8 + 3) / 4;
  k_zero<<<(n4 + 255) / 256, 256, 0, stream>>>((int4*)deg8, n4);

  long n8 = (long)N * DH / 8;
  int nConv = (int)((n8 + 255) / 256);
  int nPack = (2 * 8 * 8 * 64 * 8 + 255) / 256;
  k_prep0<<<nConv + nPack, 256, 0, stream>>>(x, xb, n8, nConv,
                                             Wself1, Wneigh1, Wself2, Wneigh2, Wp1, Wp2);

  int nper = (N + 7) / 8;
  int nchunk = 256;
  int chunkSz = (E + nchunk - 1) / nchunk;
  k_hist8<<<nchunk * 8, 256, 0, stream>>>(src, dst, deg8, E, nper, chunkSz);

  int nb1k = (M8 + 1023) / 1024;
  k_scan1<<<nb1k, 1024, 0, stream>>>(deg8, rowptr8, bsum, M8);
  k_scan2<<<1, 1024, 0, stream>>>(bsum, nb1k);
  k_scan3<<<nb1k, 1024, 0, stream>>>(rowptr8, bsum, deg8, cursor8, M8);
  k_invd<<<(N + 255) / 256, 256, 0, stream>>>(rowptr8, invdeg, N);
  k_fill8<<<nchunk * 8, 256, 0, stream>>>(src, dst, cursor8, colsrc, E, nper, chunkSz);

  int aggb = (N + 15) / 16;
  int gb = (N + 63) / 64;
  // layer 1
  k_aggregate<<<aggb, 256, 0, stream>>>((const uint4*)xb, rowptr8, colsrc, invdeg, (uint4*)nb, N);
  k_gemm<1, 0><<<gb, 256, 0, stream>>>(xb, nb, Wp1, b1, hb, N);
  // layer 2
  k_aggregate<<<aggb, 256, 0, stream>>>((const uint4*)hb, rowptr8, colsrc, invdeg, (uint4*)nb, N);
  k_gemm<0, 1><<<gb, 256, 0, stream>>>(hb, nb, Wp2, b2, d_out, N);
}